// Round 14
// baseline (381.163 us; speedup 1.0000x reference)
//
#include <hip/hip_runtime.h>
#include <hip/hip_bf16.h>

// AutoInt+MLP fused forward, MI355X gfx950.  Round 29:
//  - attn: r28 (dbuf xss, 1 barrier/layer — verified 203.6us attn / 349.1 total)
//          + two softmax VALU/latency cuts, order-of-operations only:
//          (a) exp2 prescale: K C-frag scaled by log2e before cvt_pk (48 muls)
//              -> softmax uses exp2f directly (deletes 72 muls + 1 dep level)
//          (b) tree-sum: all 12 exps issued first, then 11-add balanced tree
//              (depth 4) instead of a serial 12-add chain (saves ~30-50cyc
//              exposed latency per (s,it))
//          Evidence notes: SQ_LDS_BANK_CONFLICT==5505024 constant r18-r28 ->
//          structural b128 floor, swizzle has no headroom; occupancy ~7 waves/CU
//          under both 5- and 11-block LDS caps -> LDS shrink dead end.
//  - prep: merged single dispatcher (r27).
//  - dnn : frozen round-10 optimum.
//  HARD RULES: no 2-arg __launch_bounds__; no merged heterogeneous dispatch (attn/dnn);
//  dnn M=64 spills; dnn 512-thr & paired-field regress; attn 2-sample/4-wave FAILED
//  (r19); hoisted GROUPED short8 weight arrays FAILED (r19+r20) — banned; setprio
//  regresses (r21); NS=3 regresses (r24); barrier-free sample-per-wave regresses
//  (r25/r26); attn run-to-run variance ~±5%.

#define NF     39
#define EMB    64
#define NLAYER 3
#define VOCAB  1000
#define FLAT   2496
#define H1     512
#define H2     256
#define LOG2E  1.44269504088896340736f

typedef __attribute__((ext_vector_type(8))) short  short8;
typedef __attribute__((ext_vector_type(4))) float  floatx4;

__device__ __forceinline__ short8 ld8s(const unsigned short* p) {
    return *(const short8*)p;
}
__device__ __forceinline__ float b2f(unsigned short h) {
    union { unsigned u; float f; } x; x.u = ((unsigned)h) << 16; return x.f;
}
__device__ __forceinline__ unsigned short f2b(float f) {
    union { float f; unsigned u; } x; x.f = f;
    unsigned u = x.u;
    return (unsigned short)((u + 0x7fffu + ((u >> 16) & 1u)) >> 16);
}
// 2 floats -> packed bf16x2 in ONE VALU op (gfx950 hw cvt, RNE)
__device__ __forceinline__ unsigned cvt_pk(float a, float b) {
#if defined(__gfx950__)
    unsigned r;
    asm("v_cvt_pk_bf16_f32 %0, %1, %2" : "=v"(r) : "v"(a), "v"(b));
    return r;
#else
    return (unsigned)f2b(a) | ((unsigned)f2b(b) << 16);
#endif
}
// 4 packed bf16x2 words -> short8 MFMA operand (register re-arrangement only)
__device__ __forceinline__ short8 pk8(unsigned a, unsigned b, unsigned c, unsigned d) {
    union { unsigned u[4]; short8 s; } x;
    x.u[0] = a; x.u[1] = b; x.u[2] = c; x.u[3] = d;
    return x.s;
}

// ------- merged prep: attw_t (192 blk) + w1pack (624 blk) + w2pack (64 blk) -----------
// 880 blocks x 256 thr; bodies identical to the three original kernels, block-remapped.
__global__ void __launch_bounds__(256) prep_all(
    const float* __restrict__ WQ, const float* __restrict__ WK,
    const float* __restrict__ WV, const float* __restrict__ WR,
    const float* __restrict__ W1, const float* __restrict__ W2,
    unsigned short* __restrict__ wqt, unsigned short* __restrict__ wkt,
    unsigned short* __restrict__ wvt, unsigned short* __restrict__ wrt,
    unsigned short* __restrict__ w1p, unsigned short* __restrict__ w2p)
{
    const int b = blockIdx.x;
    if (b < 192) {
        // ---- attw_t: f32 [L][64 k][64 o] -> bf16 [L][o][k] ----------------------------
        int idx = b * 256 + threadIdx.x;            // 192*256 = 49152 = 4*3*4096 exactly
        int mat = idx / 12288;
        int rem = idx % 12288;
        int l   = rem / 4096;
        int ok  = rem % 4096;
        int o = ok >> 6, k = ok & 63;
        const float*    src = (mat == 0) ? WQ : (mat == 1) ? WK : (mat == 2) ? WV : WR;
        unsigned short* dst = (mat == 0) ? wqt : (mat == 1) ? wkt : (mat == 2) ? wvt : wrt;
        dst[l * 4096 + o * 64 + k] = f2b(src[l * 4096 + k * 64 + o]);
    } else if (b < 192 + 624) {
        // ---- w1pack: f32 [2496][512] -> bf16 fragment-linear --------------------------
        int t = (b - 192) * 256 + threadIdx.x;      // 624*256 = 159744 = 2496*64
        int lane = t & 63, grp = t >> 6;            // grp 0..2495
        int ot = grp / 78, kk = grp % 78;
        int q = lane >> 4, n = ot * 16 + (lane & 15);
        int kb = kk * 32 + q * 8;
        unsigned short* dst = w1p + grp * 512 + lane * 8;
        #pragma unroll
        for (int j = 0; j < 8; ++j)
            dst[j] = f2b(W1[(kb + j) * 512 + n]);
    } else {
        // ---- w2pack: f32 [512][256] -> bf16 fragment-linear ---------------------------
        int t = (b - 816) * 256 + threadIdx.x;      // 64*256 = 16384 = 256*64
        int lane = t & 63, grp = t >> 6;            // grp 0..255
        int ot = grp / 16, kk = grp % 16;
        int q = lane >> 4, n = ot * 16 + (lane & 15);
        int kb = kk * 32 + q * 8;
        unsigned short* dst = w2p + grp * 512 + lane * 8;
        #pragma unroll
        for (int j = 0; j < 8; ++j)
            dst[j] = f2b(W2[(kb + j) * 256 + n]);
    }
}

// ------- fused attention: 2 samples/block, 2 waves (wave = head, BOTH samples) --------
// 8192 blocks x 128 thr. LDS: xss 2(buf) x 2(sample) x 6912 + red 16 = 27664 B.
// Double-buffered xss: layer L reads buf L&1, writes buf (L+1)&1 -> ONE barrier/layer.
__global__ void __launch_bounds__(128) attn_kernel(
    const int* __restrict__ X,
    const float* __restrict__ embf,
    const unsigned short* __restrict__ wqt,
    const unsigned short* __restrict__ wkt,
    const unsigned short* __restrict__ wvt,
    const unsigned short* __restrict__ wrt,
    const float* __restrict__ wlinf,
    float* __restrict__ att_out)
{
    __shared__ unsigned short xss[2][2][48 * 72];  // [buf][sample][token 48][col 64+8pad]
    __shared__ float red[2][2];                    // [sample][wave]

    const int tid  = threadIdx.x;
    const int wid  = tid >> 6;          // 0..1
    const int lane = tid & 63;
    const int h    = wid;               // head
    const int quad = lane >> 4;
    const int l16  = lane & 15;
    const int samp0 = blockIdx.x * 2;

    // ---- embedding gather: wave fills its head's cols for BOTH samples into buf 0 -----
    {
        const int tq = lane >> 4;            // 0..3
        const int cp = (lane & 15) * 2;      // 0,2,..,30
        const int col = h * 32 + cp;
        #pragma unroll
        for (int s = 0; s < 2; ++s) {
            const int* xrow = X + (samp0 + s) * NF;
            #pragma unroll
            for (int t0 = 0; t0 < 48; t0 += 4) {
                int t = t0 + tq;
                unsigned pk = 0;
                if (t < NF) {
                    int row = xrow[t] + t * VOCAB;
                    const float2 v = *(const float2*)&embf[row * EMB + col];
                    pk = cvt_pk(v.x, v.y);
                }
                *(unsigned*)&xss[0][s][t * 72 + col] = pk;   // rows 39..47 zeroed
            }
        }
    }
    __syncthreads();

    // ---- hoisted per-lane constants ---------------------------------------------------
    const int wro = (h * 32 + l16) * 64 + quad * 8;    // +ot*1024 per 16-row tile
    const unsigned short* wqp = wqt + wro;
    const unsigned short* wkp = wkt + wro;
    const unsigned short* wvq = wvt + wro;
    const unsigned short* wrp = wrt + wro;
    float m2[4];                                       // jt=2 softmax mask (j=32+quad*4+r)
    #pragma unroll
    for (int r = 0; r < 4; ++r)
        m2[r] = (32 + quad * 4 + r < NF) ? 1.f : 0.f;

    for (int layer = 0; layer < NLAYER; ++layer) {
        const int rb = layer & 1, wb = rb ^ 1;

        // ---- xss fragments for both samples (reads buf rb; no barrier needed after:
        //      this layer's writes go to buf wb, disjoint) ------------------------------
        short8 xf[2][3][2];
        #pragma unroll
        for (int s = 0; s < 2; ++s)
            #pragma unroll
            for (int tt = 0; tt < 3; ++tt)
                #pragma unroll
                for (int kk = 0; kk < 2; ++kk)
                    xf[s][tt][kk] = ld8s(&xss[rb][s][(tt * 16 + l16) * 72 + kk * 32 + quad * 8]);

        // ---- Q,K projections, weights SHARED across samples ---------------------------
        // K C-frag pre-scaled by log2e -> softmax uses exp2 directly (saves the
        // per-exp v_mul; identical error class: bf16-rounding of scaled K)
        unsigned qw[2][2][3][2], kw[2][2][3][2];   // [s][ot][tt][word]
        #pragma unroll
        for (int mat = 0; mat < 2; ++mat) {
            const unsigned short* wt = mat ? wkp : wqp;
            #pragma unroll
            for (int ot = 0; ot < 2; ++ot) {
                short8 w0 = ld8s(wt + ot * 1024);
                short8 w1 = ld8s(wt + ot * 1024 + 32);
                #pragma unroll
                for (int s = 0; s < 2; ++s)
                    #pragma unroll
                    for (int tt = 0; tt < 3; ++tt) {
                        floatx4 c = {0.f, 0.f, 0.f, 0.f};
                        c = __builtin_amdgcn_mfma_f32_16x16x32_bf16(w0, xf[s][tt][0], c, 0, 0, 0);
                        c = __builtin_amdgcn_mfma_f32_16x16x32_bf16(w1, xf[s][tt][1], c, 0, 0, 0);
                        if (mat == 0) {
                            qw[s][ot][tt][0] = cvt_pk(c[0], c[1]);
                            qw[s][ot][tt][1] = cvt_pk(c[2], c[3]);
                        } else {
                            kw[s][ot][tt][0] = cvt_pk(c[0] * LOG2E, c[1] * LOG2E);
                            kw[s][ot][tt][1] = cvt_pk(c[2] * LOG2E, c[3] * LOG2E);
                        }
                    }
            }
        }

        // ---- R projection -> O init (weights shared) ----------------------------------
        floatx4 O[2][2][3];                         // [s][dt][it]
        #pragma unroll
        for (int dt = 0; dt < 2; ++dt) {
            short8 w0 = ld8s(wrp + dt * 1024);
            short8 w1 = ld8s(wrp + dt * 1024 + 32);
            #pragma unroll
            for (int s = 0; s < 2; ++s)
                #pragma unroll
                for (int it = 0; it < 3; ++it) {
                    floatx4 c = {0.f, 0.f, 0.f, 0.f};
                    c = __builtin_amdgcn_mfma_f32_16x16x32_bf16(w0, xf[s][it][0], c, 0, 0, 0);
                    c = __builtin_amdgcn_mfma_f32_16x16x32_bf16(w1, xf[s][it][1], c, 0, 0, 0);
                    O[s][dt][it] = c;
                }
        }

        // ---- V projection -> vw (weights shared; xf dies here) ------------------------
        unsigned vw[2][3][2][2];                    // [s][mt][nt][word]
        #pragma unroll
        for (int nt = 0; nt < 2; ++nt) {
            short8 w0 = ld8s(wvq + nt * 1024);
            short8 w1 = ld8s(wvq + nt * 1024 + 32);
            #pragma unroll
            for (int s = 0; s < 2; ++s)
                #pragma unroll
                for (int mt = 0; mt < 3; ++mt) {
                    floatx4 c = {0.f, 0.f, 0.f, 0.f};
                    c = __builtin_amdgcn_mfma_f32_16x16x32_bf16(xf[s][mt][0], w0, c, 0, 0, 0);
                    c = __builtin_amdgcn_mfma_f32_16x16x32_bf16(xf[s][mt][1], w1, c, 0, 0, 0);
                    vw[s][mt][nt][0] = cvt_pk(c[0], c[1]);
                    vw[s][mt][nt][1] = cvt_pk(c[2], c[3]);
                }
        }

        // ---- per sample: S^T (=S*log2e) then exp2-softmax with tree-sum ---------------
        unsigned pw[2][3][3][2];                    // [s][jt][it][word]
        #pragma unroll
        for (int s = 0; s < 2; ++s) {
            floatx4 ST[3][3];
            #pragma unroll
            for (int jt = 0; jt < 3; ++jt) {
                short8 a = pk8(kw[s][0][jt][0], kw[s][0][jt][1], kw[s][1][jt][0], kw[s][1][jt][1]);
                #pragma unroll
                for (int it = 0; it < 3; ++it) {
                    short8 b = pk8(qw[s][0][it][0], qw[s][0][it][1], qw[s][1][it][0], qw[s][1][it][1]);
                    floatx4 z = {0.f, 0.f, 0.f, 0.f};
                    ST[jt][it] = __builtin_amdgcn_mfma_f32_16x16x32_bf16(a, b, z, 0, 0, 0);
                }
            }
            #pragma unroll
            for (int it = 0; it < 3; ++it) {
                // all 12 exps issued first (no serial chain through them) ...
                float p[3][4];
                #pragma unroll
                for (int jt = 0; jt < 3; ++jt)
                    #pragma unroll
                    for (int r = 0; r < 4; ++r) {
                        float e = exp2f(ST[jt][it][r]);
                        if (jt == 2) e *= m2[r];
                        p[jt][r] = e;
                    }
                // ... then an 11-add balanced tree (depth 4) instead of 12-chain
                float s01 = (p[0][0] + p[0][1]) + (p[0][2] + p[0][3]);
                float s23 = (p[1][0] + p[1][1]) + (p[1][2] + p[1][3]);
                float s45 = (p[2][0] + p[2][1]) + (p[2][2] + p[2][3]);
                float sum = (s01 + s23) + s45;
                sum += __shfl_xor(sum, 16, 64);
                sum += __shfl_xor(sum, 32, 64);
                float inv = 1.0f / sum;
                #pragma unroll
                for (int jt = 0; jt < 3; ++jt) {
                    pw[s][jt][it][0] = cvt_pk(p[jt][0] * inv, p[jt][1] * inv);
                    pw[s][jt][it][1] = cvt_pk(p[jt][2] * inv, p[jt][3] * inv);
                }
            }
        }

        // ---- O^T += V^T @ P^T per sample ----------------------------------------------
        #pragma unroll
        for (int s = 0; s < 2; ++s)
            #pragma unroll
            for (int dt = 0; dt < 2; ++dt) {
                short8 a01 = pk8(vw[s][0][dt][0], vw[s][0][dt][1], vw[s][1][dt][0], vw[s][1][dt][1]);
                short8 a2  = pk8(vw[s][2][dt][0], vw[s][2][dt][1], 0u, 0u);
                #pragma unroll
                for (int it = 0; it < 3; ++it) {
                    short8 b01 = pk8(pw[s][0][it][0], pw[s][0][it][1], pw[s][1][it][0], pw[s][1][it][1]);
                    short8 b2  = pk8(pw[s][2][it][0], pw[s][2][it][1], 0u, 0u);
                    O[s][dt][it] = __builtin_amdgcn_mfma_f32_16x16x32_bf16(a01, b01, O[s][dt][it], 0, 0, 0);
                    O[s][dt][it] = __builtin_amdgcn_mfma_f32_16x16x32_bf16(a2,  b2,  O[s][dt][it], 0, 0, 0);
                }
            }

        // ---- next x = relu(O^T): write xss[wb][s][tok][d] (disjoint from reads) -------
        #pragma unroll
        for (int s = 0; s < 2; ++s)
            #pragma unroll
            for (int dt = 0; dt < 2; ++dt)
                #pragma unroll
                for (int it = 0; it < 3; ++it) {
                    uint2 w;
                    w.x = cvt_pk(fmaxf(O[s][dt][it][0], 0.f), fmaxf(O[s][dt][it][1], 0.f));
                    w.y = cvt_pk(fmaxf(O[s][dt][it][2], 0.f), fmaxf(O[s][dt][it][3], 0.f));
                    *(uint2*)&xss[wb][s][(it * 16 + l16) * 72 + h * 32 + dt * 16 + quad * 4] = w;
                }

        __syncthreads();   // buf wb complete before next layer (or logit) reads it

        wqp += 4096; wkp += 4096; wvq += 4096; wrp += 4096;   // next layer's weights
    }

    // ---- att logit: relu( att_flat . Wlin ), both samples (x lives in buf NLAYER&1) ---
    {
        const unsigned short* xfin0 = xss[NLAYER & 1][0];
        const unsigned short* xfin1 = xss[NLAYER & 1][1];
        const int c = lane & 31, tp = lane >> 5;
        const int col = h * 32 + c;
        #pragma unroll
        for (int s = 0; s < 2; ++s) {
            const unsigned short* xf = s ? xfin1 : xfin0;
            float acc = 0.f;
            for (int t0 = 0; t0 < 40; t0 += 2) {
                int t = t0 + tp;
                if (t < NF)
                    acc += b2f(xf[t * 72 + col]) * wlinf[t * EMB + col];
            }
            #pragma unroll
            for (int off = 1; off < 64; off <<= 1)
                acc += __shfl_xor(acc, off, 64);
            if (lane == 0) red[s][wid] = acc;
        }
        __syncthreads();
        if (tid == 0) {
            att_out[samp0]     = fmaxf(red[0][0] + red[0][1], 0.f);
            att_out[samp0 + 1] = fmaxf(red[1][0] + red[1][1], 0.f);
        }
    }
}

// ------- DNN (ROUND-10 VERBATIM, frozen optimum): 32-sample tile, packed B-loads ------
// 512 blocks x 256 thr. LDS: ea 9216 + h1s 33280 = 42496 B.
__global__ void __launch_bounds__(256) dnn_kernel(
    const int* __restrict__ X,
    const float* __restrict__ embf,
    const unsigned short* __restrict__ w1p,
    const float* __restrict__ b1v,
    const unsigned short* __restrict__ w2p,
    const float* __restrict__ b2v,
    const float* __restrict__ w3v,
    const float* __restrict__ b3v,
    const float* __restrict__ att_in,
    float* __restrict__ out)
{
    __shared__ unsigned short ea[2][32 * 72];     // double-buffered [sample 32][64+8pad]
    __shared__ unsigned short h1s[32 * 520];      // h1 [32][512+8pad]; h2 [32][264] aliases
    unsigned short* h2s = h1s;

    const int tid  = threadIdx.x;
    const int wid  = tid >> 6, lane = tid & 63, quad = lane >> 4, l16 = lane & 15;
    const int S0   = blockIdx.x * 32;

    floatx4 C1[2][8];
    #pragma unroll
    for (int mt = 0; mt < 2; ++mt)
        #pragma unroll
        for (int nt = 0; nt < 8; ++nt)
            C1[mt][nt] = (floatx4){0.f, 0.f, 0.f, 0.f};

    const int gs = tid >> 3;        // 0..31 sample for staging
    const int gg = tid & 7;         // 8 floats each

    // prologue: stage field 0 into ea[0]
    {
        int row = X[(S0 + gs) * NF + 0];
        const float4* src = (const float4*)&embf[row * EMB + gg * 8];
        float4 v0 = src[0], v1 = src[1];
        uint4 u;
        u.x = cvt_pk(v0.x, v0.y); u.y = cvt_pk(v0.z, v0.w);
        u.z = cvt_pk(v1.x, v1.y); u.w = cvt_pk(v1.z, v1.w);
        *(uint4*)&ea[0][gs * 72 + gg * 8] = u;
    }
    __syncthreads();

    // ---- phase 1: h1 = emb(32 x 2496) @ W1, K streamed per field, dbuf, 1 sync/iter ---
    for (int f = 0; f < NF; ++f) {
        if (f < NF - 1) {   // stage next field into the other buffer (disjoint from reads)
            int row = X[(S0 + gs) * NF + f + 1] + (f + 1) * VOCAB;
            const float4* src = (const float4*)&embf[row * EMB + gg * 8];
            float4 v0 = src[0], v1 = src[1];
            uint4 u;
            u.x = cvt_pk(v0.x, v0.y); u.y = cvt_pk(v0.z, v0.w);
            u.z = cvt_pk(v1.x, v1.y); u.w = cvt_pk(v1.z, v1.w);
            *(uint4*)&ea[(f + 1) & 1][gs * 72 + gg * 8] = u;
        }
        const unsigned short* eac = ea[f & 1];
        short8 a[2][2];
        #pragma unroll
        for (int mt = 0; mt < 2; ++mt) {
            a[mt][0] = ld8s(&eac[(mt * 16 + l16) * 72 + quad * 8]);
            a[mt][1] = ld8s(&eac[(mt * 16 + l16) * 72 + 32 + quad * 8]);
        }
        #pragma unroll
        for (int nt = 0; nt < 8; ++nt) {
            const unsigned short* bp = w1p + (((wid * 8 + nt) * 78 + f * 2) * 64 + lane) * 8;
            short8 b0 = ld8s(bp);
            short8 b1 = ld8s(bp + 512);
            #pragma unroll
            for (int mt = 0; mt < 2; ++mt) {
                C1[mt][nt] = __builtin_amdgcn_mfma_f32_16x16x32_bf16(a[mt][0], b0, C1[mt][nt], 0, 0, 0);
                C1[mt][nt] = __builtin_amdgcn_mfma_f32_16x16x32_bf16(a[mt][1], b1, C1[mt][nt], 0, 0, 0);
            }
        }
        __syncthreads();   // waves may not drift >1 iter: protects both ea buffers
    }

    // bias + relu, write ALL of h1 to LDS (each wave owns 128 cols)
    #pragma unroll
    for (int nt = 0; nt < 8; ++nt) {
        float bb = b1v[wid * 128 + nt * 16 + l16];
        #pragma unroll
        for (int mt = 0; mt < 2; ++mt) {
            #pragma unroll
            for (int r = 0; r < 4; ++r) {
                float v = fmaxf(C1[mt][nt][r] + bb, 0.f);
                h1s[(mt * 16 + quad * 4 + r) * 520 + wid * 128 + nt * 16 + l16] = f2b(v);
            }
        }
    }
    __syncthreads();

    // ---- phase 2: h2 = h1(32 x 512) @ W2, single pass, wave owns 64 N-cols ------------
    floatx4 C2[2][4];
    #pragma unroll
    for (int mt = 0; mt < 2; ++mt)
        #pragma unroll
        for (int nt = 0; nt < 4; ++nt)
            C2[mt][nt] = (floatx4){0.f, 0.f, 0.f, 0.f};

    #pragma unroll 4
    for (int kk = 0; kk < 16; ++kk) {
        short8 a0 = ld8s(&h1s[(l16) * 520 + kk * 32 + quad * 8]);
        short8 a1 = ld8s(&h1s[(16 + l16) * 520 + kk * 32 + quad * 8]);
        #pragma unroll
        for (int nt = 0; nt < 4; ++nt) {
            short8 b = ld8s(w2p + (((wid * 4 + nt) * 16 + kk) * 64 + lane) * 8);
            C2[0][nt] = __builtin_amdgcn_mfma_f32_16x16x32_bf16(a0, b, C2[0][nt], 0, 0, 0);
            C2[1][nt] = __builtin_amdgcn_mfma_f32_16x16x32_bf16(a1, b, C2[1][nt], 0, 0, 0);
        }
    }
    __syncthreads();    // h1 reads complete -> safe to alias h2s onto h1s

    #pragma unroll
    for (int nt = 0; nt < 4; ++nt) {
        float bb = b2v[wid * 64 + nt * 16 + l16];
        #pragma unroll
        for (int mt = 0; mt < 2; ++mt)
            #pragma unroll
            for (int r = 0; r < 4; ++r)
                h2s[(mt * 16 + quad * 4 + r) * 264 + wid * 64 + nt * 16 + l16] =
                    f2b(fmaxf(C2[mt][nt][r] + bb, 0.f));
    }
    __syncthreads();

    // ---- phase 3: dnn = relu(h2 . W3 + b3); out = sigmoid(att + dnn), f32 -------------
    {
        int s = tid >> 3, part = tid & 7;     // 8 lanes per sample, 32 elems each
        float acc = 0.f;
        #pragma unroll 8
        for (int j = 0; j < 32; ++j) {
            int jj = part * 32 + j;
            acc += b2f(h2s[s * 264 + jj]) * w3v[jj];
        }
        acc += __shfl_xor(acc, 1, 64);
        acc += __shfl_xor(acc, 2, 64);
        acc += __shfl_xor(acc, 4, 64);
        if (part == 0) {
            float dnn = fmaxf(acc + b3v[0], 0.f);
            float v = dnn + att_in[S0 + s];
            out[S0 + s] = 1.f / (1.f + __expf(-v));
        }
    }
}

extern "C" void kernel_launch(void* const* d_in, const int* in_sizes, int n_in,
                              void* d_out, int out_size, void* d_ws, size_t ws_size,
                              hipStream_t stream)
{
    (void)in_sizes; (void)n_in; (void)out_size; (void)ws_size;

    const int*   X    = (const int*)d_in[0];
    const float* emb  = (const float*)d_in[1];
    const float* WQ   = (const float*)d_in[2];
    const float* WK   = (const float*)d_in[3];
    const float* WV   = (const float*)d_in[4];
    const float* WR   = (const float*)d_in[5];
    const float* W1   = (const float*)d_in[6];
    const float* b1   = (const float*)d_in[7];
    const float* W2   = (const float*)d_in[8];
    const float* b2   = (const float*)d_in[9];
    const float* W3   = (const float*)d_in[10];
    const float* b3   = (const float*)d_in[11];
    const float* Wlin = (const float*)d_in[12];

    char* ws = (char*)d_ws;
    float*          att_logit = (float*)ws;                          // 16384 f32 = 64KB
    unsigned short* wqt = (unsigned short*)(ws + 65536);             // 3*4096 shorts each
    unsigned short* wkt = wqt + 3 * 4096;
    unsigned short* wvt = wkt + 3 * 4096;
    unsigned short* wrt = wvt + 3 * 4096;
    unsigned short* w1p = wrt + 3 * 4096;                            // 2496*512 shorts
    unsigned short* w2p = w1p + 2496 * 512;                          // 256*512 shorts

    prep_all<<<880, 256, 0, stream>>>(WQ, WK, WV, WR, W1, W2,
                                      wqt, wkt, wvt, wrt, w1p, w2p);
    attn_kernel<<<8192, 128, 0, stream>>>(X, emb, wqt, wkt, wvt, wrt, Wlin, att_logit);
    dnn_kernel<<<512, 256, 0, stream>>>(X, emb, w1p, b1, w2p, b2, W3, b3, att_logit,
                                        (float*)d_out);
}

// Round 15
// 358.871 us; speedup vs baseline: 1.0621x; 1.0621x over previous
//
#include <hip/hip_runtime.h>
#include <hip/hip_bf16.h>

// AutoInt+MLP fused forward, MI355X gfx950.  Round 30 (FINAL consolidation):
//  - attn: ROUND-28 RESTORED VERBATIM — verified best (attn 203.6us, total 349.1us).
//          r29's exp2f+tree-sum regressed (+30us): exp2f is libm-precise, expands to
//          guarded OCML code, NOT bare v_exp_f32 — only __-intrinsics are fast paths.
//          Structure: 2 samples/wave ILP, dbuf xss (1 barrier/layer), merged prep.
//          Lever ledger (all counter-verified): TLP up r19/r25/r26 fail; ILP>2 r24
//          VGPR cliff; barriers<1/layer r25/r26 regress; setprio r21 regress; VALU
//          micro-cuts r22 +1% / r29 -8%; dbuf barrier-halving r28 WIN (-18us).
//  - dnn : frozen round-10 optimum.
//  HARD RULES: no 2-arg __launch_bounds__; no merged heterogeneous dispatch (attn/dnn);
//  dnn M=64 spills; dnn 512-thr & paired-field regress; attn 2-sample/4-wave FAILED
//  (r19); hoisted GROUPED short8 weight arrays FAILED (r19+r20) — banned; setprio
//  regresses (r21); NS=3 regresses (r24); barrier-free sample-per-wave regresses
//  (r25/r26); exp2f/tree-sum regresses (r29); attn run-to-run variance ~±5%.

#define NF     39
#define EMB    64
#define NLAYER 3
#define VOCAB  1000
#define FLAT   2496
#define H1     512
#define H2     256

typedef __attribute__((ext_vector_type(8))) short  short8;
typedef __attribute__((ext_vector_type(4))) float  floatx4;

__device__ __forceinline__ short8 ld8s(const unsigned short* p) {
    return *(const short8*)p;
}
__device__ __forceinline__ float b2f(unsigned short h) {
    union { unsigned u; float f; } x; x.u = ((unsigned)h) << 16; return x.f;
}
__device__ __forceinline__ unsigned short f2b(float f) {
    union { float f; unsigned u; } x; x.f = f;
    unsigned u = x.u;
    return (unsigned short)((u + 0x7fffu + ((u >> 16) & 1u)) >> 16);
}
// 2 floats -> packed bf16x2 in ONE VALU op (gfx950 hw cvt, RNE)
__device__ __forceinline__ unsigned cvt_pk(float a, float b) {
#if defined(__gfx950__)
    unsigned r;
    asm("v_cvt_pk_bf16_f32 %0, %1, %2" : "=v"(r) : "v"(a), "v"(b));
    return r;
#else
    return (unsigned)f2b(a) | ((unsigned)f2b(b) << 16);
#endif
}
// 4 packed bf16x2 words -> short8 MFMA operand (register re-arrangement only)
__device__ __forceinline__ short8 pk8(unsigned a, unsigned b, unsigned c, unsigned d) {
    union { unsigned u[4]; short8 s; } x;
    x.u[0] = a; x.u[1] = b; x.u[2] = c; x.u[3] = d;
    return x.s;
}

// ------- merged prep: attw_t (192 blk) + w1pack (624 blk) + w2pack (64 blk) -----------
// 880 blocks x 256 thr; bodies identical to the three original kernels, block-remapped.
__global__ void __launch_bounds__(256) prep_all(
    const float* __restrict__ WQ, const float* __restrict__ WK,
    const float* __restrict__ WV, const float* __restrict__ WR,
    const float* __restrict__ W1, const float* __restrict__ W2,
    unsigned short* __restrict__ wqt, unsigned short* __restrict__ wkt,
    unsigned short* __restrict__ wvt, unsigned short* __restrict__ wrt,
    unsigned short* __restrict__ w1p, unsigned short* __restrict__ w2p)
{
    const int b = blockIdx.x;
    if (b < 192) {
        // ---- attw_t: f32 [L][64 k][64 o] -> bf16 [L][o][k] ----------------------------
        int idx = b * 256 + threadIdx.x;            // 192*256 = 49152 = 4*3*4096 exactly
        int mat = idx / 12288;
        int rem = idx % 12288;
        int l   = rem / 4096;
        int ok  = rem % 4096;
        int o = ok >> 6, k = ok & 63;
        const float*    src = (mat == 0) ? WQ : (mat == 1) ? WK : (mat == 2) ? WV : WR;
        unsigned short* dst = (mat == 0) ? wqt : (mat == 1) ? wkt : (mat == 2) ? wvt : wrt;
        dst[l * 4096 + o * 64 + k] = f2b(src[l * 4096 + k * 64 + o]);
    } else if (b < 192 + 624) {
        // ---- w1pack: f32 [2496][512] -> bf16 fragment-linear --------------------------
        int t = (b - 192) * 256 + threadIdx.x;      // 624*256 = 159744 = 2496*64
        int lane = t & 63, grp = t >> 6;            // grp 0..2495
        int ot = grp / 78, kk = grp % 78;
        int q = lane >> 4, n = ot * 16 + (lane & 15);
        int kb = kk * 32 + q * 8;
        unsigned short* dst = w1p + grp * 512 + lane * 8;
        #pragma unroll
        for (int j = 0; j < 8; ++j)
            dst[j] = f2b(W1[(kb + j) * 512 + n]);
    } else {
        // ---- w2pack: f32 [512][256] -> bf16 fragment-linear ---------------------------
        int t = (b - 816) * 256 + threadIdx.x;      // 64*256 = 16384 = 256*64
        int lane = t & 63, grp = t >> 6;            // grp 0..255
        int ot = grp / 16, kk = grp % 16;
        int q = lane >> 4, n = ot * 16 + (lane & 15);
        int kb = kk * 32 + q * 8;
        unsigned short* dst = w2p + grp * 512 + lane * 8;
        #pragma unroll
        for (int j = 0; j < 8; ++j)
            dst[j] = f2b(W2[(kb + j) * 256 + n]);
    }
}

// ------- fused attention: 2 samples/block, 2 waves (wave = head, BOTH samples) --------
// 8192 blocks x 128 thr. LDS: xss 2(buf) x 2(sample) x 6912 + red 16 = 27664 B.
// Double-buffered xss: layer L reads buf L&1, writes buf (L+1)&1 -> ONE barrier/layer.
__global__ void __launch_bounds__(128) attn_kernel(
    const int* __restrict__ X,
    const float* __restrict__ embf,
    const unsigned short* __restrict__ wqt,
    const unsigned short* __restrict__ wkt,
    const unsigned short* __restrict__ wvt,
    const unsigned short* __restrict__ wrt,
    const float* __restrict__ wlinf,
    float* __restrict__ att_out)
{
    __shared__ unsigned short xss[2][2][48 * 72];  // [buf][sample][token 48][col 64+8pad]
    __shared__ float red[2][2];                    // [sample][wave]

    const int tid  = threadIdx.x;
    const int wid  = tid >> 6;          // 0..1
    const int lane = tid & 63;
    const int h    = wid;               // head
    const int quad = lane >> 4;
    const int l16  = lane & 15;
    const int samp0 = blockIdx.x * 2;

    // ---- embedding gather: wave fills its head's cols for BOTH samples into buf 0 -----
    {
        const int tq = lane >> 4;            // 0..3
        const int cp = (lane & 15) * 2;      // 0,2,..,30
        const int col = h * 32 + cp;
        #pragma unroll
        for (int s = 0; s < 2; ++s) {
            const int* xrow = X + (samp0 + s) * NF;
            #pragma unroll
            for (int t0 = 0; t0 < 48; t0 += 4) {
                int t = t0 + tq;
                unsigned pk = 0;
                if (t < NF) {
                    int row = xrow[t] + t * VOCAB;
                    const float2 v = *(const float2*)&embf[row * EMB + col];
                    pk = cvt_pk(v.x, v.y);
                }
                *(unsigned*)&xss[0][s][t * 72 + col] = pk;   // rows 39..47 zeroed
            }
        }
    }
    __syncthreads();

    // ---- hoisted per-lane constants ---------------------------------------------------
    const int wro = (h * 32 + l16) * 64 + quad * 8;    // +ot*1024 per 16-row tile
    const unsigned short* wqp = wqt + wro;
    const unsigned short* wkp = wkt + wro;
    const unsigned short* wvq = wvt + wro;
    const unsigned short* wrp = wrt + wro;
    float m2[4];                                       // jt=2 softmax mask (j=32+quad*4+r)
    #pragma unroll
    for (int r = 0; r < 4; ++r)
        m2[r] = (32 + quad * 4 + r < NF) ? 1.f : 0.f;

    for (int layer = 0; layer < NLAYER; ++layer) {
        const int rb = layer & 1, wb = rb ^ 1;

        // ---- xss fragments for both samples (reads buf rb; no barrier needed after:
        //      this layer's writes go to buf wb, disjoint) ------------------------------
        short8 xf[2][3][2];
        #pragma unroll
        for (int s = 0; s < 2; ++s)
            #pragma unroll
            for (int tt = 0; tt < 3; ++tt)
                #pragma unroll
                for (int kk = 0; kk < 2; ++kk)
                    xf[s][tt][kk] = ld8s(&xss[rb][s][(tt * 16 + l16) * 72 + kk * 32 + quad * 8]);

        // ---- Q,K projections, weights SHARED across samples ---------------------------
        unsigned qw[2][2][3][2], kw[2][2][3][2];   // [s][ot][tt][word]
        #pragma unroll
        for (int mat = 0; mat < 2; ++mat) {
            const unsigned short* wt = mat ? wkp : wqp;
            #pragma unroll
            for (int ot = 0; ot < 2; ++ot) {
                short8 w0 = ld8s(wt + ot * 1024);
                short8 w1 = ld8s(wt + ot * 1024 + 32);
                #pragma unroll
                for (int s = 0; s < 2; ++s)
                    #pragma unroll
                    for (int tt = 0; tt < 3; ++tt) {
                        floatx4 c = {0.f, 0.f, 0.f, 0.f};
                        c = __builtin_amdgcn_mfma_f32_16x16x32_bf16(w0, xf[s][tt][0], c, 0, 0, 0);
                        c = __builtin_amdgcn_mfma_f32_16x16x32_bf16(w1, xf[s][tt][1], c, 0, 0, 0);
                        if (mat == 0) {
                            qw[s][ot][tt][0] = cvt_pk(c[0], c[1]);
                            qw[s][ot][tt][1] = cvt_pk(c[2], c[3]);
                        } else {
                            kw[s][ot][tt][0] = cvt_pk(c[0], c[1]);
                            kw[s][ot][tt][1] = cvt_pk(c[2], c[3]);
                        }
                    }
            }
        }

        // ---- R projection -> O init (weights shared) ----------------------------------
        floatx4 O[2][2][3];                         // [s][dt][it]
        #pragma unroll
        for (int dt = 0; dt < 2; ++dt) {
            short8 w0 = ld8s(wrp + dt * 1024);
            short8 w1 = ld8s(wrp + dt * 1024 + 32);
            #pragma unroll
            for (int s = 0; s < 2; ++s)
                #pragma unroll
                for (int it = 0; it < 3; ++it) {
                    floatx4 c = {0.f, 0.f, 0.f, 0.f};
                    c = __builtin_amdgcn_mfma_f32_16x16x32_bf16(w0, xf[s][it][0], c, 0, 0, 0);
                    c = __builtin_amdgcn_mfma_f32_16x16x32_bf16(w1, xf[s][it][1], c, 0, 0, 0);
                    O[s][dt][it] = c;
                }
        }

        // ---- V projection -> vw (weights shared; xf dies here) ------------------------
        unsigned vw[2][3][2][2];                    // [s][mt][nt][word]
        #pragma unroll
        for (int nt = 0; nt < 2; ++nt) {
            short8 w0 = ld8s(wvq + nt * 1024);
            short8 w1 = ld8s(wvq + nt * 1024 + 32);
            #pragma unroll
            for (int s = 0; s < 2; ++s)
                #pragma unroll
                for (int mt = 0; mt < 3; ++mt) {
                    floatx4 c = {0.f, 0.f, 0.f, 0.f};
                    c = __builtin_amdgcn_mfma_f32_16x16x32_bf16(xf[s][mt][0], w0, c, 0, 0, 0);
                    c = __builtin_amdgcn_mfma_f32_16x16x32_bf16(xf[s][mt][1], w1, c, 0, 0, 0);
                    vw[s][mt][nt][0] = cvt_pk(c[0], c[1]);
                    vw[s][mt][nt][1] = cvt_pk(c[2], c[3]);
                }
        }

        // ---- per sample: S^T then softmax (ONE ST tensor live at a time) --------------
        unsigned pw[2][3][3][2];                    // [s][jt][it][word]
        #pragma unroll
        for (int s = 0; s < 2; ++s) {
            floatx4 ST[3][3];
            #pragma unroll
            for (int jt = 0; jt < 3; ++jt) {
                short8 a = pk8(kw[s][0][jt][0], kw[s][0][jt][1], kw[s][1][jt][0], kw[s][1][jt][1]);
                #pragma unroll
                for (int it = 0; it < 3; ++it) {
                    short8 b = pk8(qw[s][0][it][0], qw[s][0][it][1], qw[s][1][it][0], qw[s][1][it][1]);
                    floatx4 z = {0.f, 0.f, 0.f, 0.f};
                    ST[jt][it] = __builtin_amdgcn_mfma_f32_16x16x32_bf16(a, b, z, 0, 0, 0);
                }
            }
            #pragma unroll
            for (int it = 0; it < 3; ++it) {
                float p[3][4];
                float sum = 0.f;
                #pragma unroll
                for (int jt = 0; jt < 3; ++jt)
                    #pragma unroll
                    for (int r = 0; r < 4; ++r) {
                        float e = __expf(ST[jt][it][r]);
                        if (jt == 2) e *= m2[r];
                        p[jt][r] = e;
                        sum += e;
                    }
                sum += __shfl_xor(sum, 16, 64);
                sum += __shfl_xor(sum, 32, 64);
                float inv = 1.0f / sum;
                #pragma unroll
                for (int jt = 0; jt < 3; ++jt) {
                    pw[s][jt][it][0] = cvt_pk(p[jt][0] * inv, p[jt][1] * inv);
                    pw[s][jt][it][1] = cvt_pk(p[jt][2] * inv, p[jt][3] * inv);
                }
            }
        }

        // ---- O^T += V^T @ P^T per sample ----------------------------------------------
        #pragma unroll
        for (int s = 0; s < 2; ++s)
            #pragma unroll
            for (int dt = 0; dt < 2; ++dt) {
                short8 a01 = pk8(vw[s][0][dt][0], vw[s][0][dt][1], vw[s][1][dt][0], vw[s][1][dt][1]);
                short8 a2  = pk8(vw[s][2][dt][0], vw[s][2][dt][1], 0u, 0u);
                #pragma unroll
                for (int it = 0; it < 3; ++it) {
                    short8 b01 = pk8(pw[s][0][it][0], pw[s][0][it][1], pw[s][1][it][0], pw[s][1][it][1]);
                    short8 b2  = pk8(pw[s][2][it][0], pw[s][2][it][1], 0u, 0u);
                    O[s][dt][it] = __builtin_amdgcn_mfma_f32_16x16x32_bf16(a01, b01, O[s][dt][it], 0, 0, 0);
                    O[s][dt][it] = __builtin_amdgcn_mfma_f32_16x16x32_bf16(a2,  b2,  O[s][dt][it], 0, 0, 0);
                }
            }

        // ---- next x = relu(O^T): write xss[wb][s][tok][d] (disjoint from reads) -------
        #pragma unroll
        for (int s = 0; s < 2; ++s)
            #pragma unroll
            for (int dt = 0; dt < 2; ++dt)
                #pragma unroll
                for (int it = 0; it < 3; ++it) {
                    uint2 w;
                    w.x = cvt_pk(fmaxf(O[s][dt][it][0], 0.f), fmaxf(O[s][dt][it][1], 0.f));
                    w.y = cvt_pk(fmaxf(O[s][dt][it][2], 0.f), fmaxf(O[s][dt][it][3], 0.f));
                    *(uint2*)&xss[wb][s][(it * 16 + l16) * 72 + h * 32 + dt * 16 + quad * 4] = w;
                }

        __syncthreads();   // buf wb complete before next layer (or logit) reads it

        wqp += 4096; wkp += 4096; wvq += 4096; wrp += 4096;   // next layer's weights
    }

    // ---- att logit: relu( att_flat . Wlin ), both samples (x lives in buf NLAYER&1) ---
    {
        const unsigned short* xfin0 = xss[NLAYER & 1][0];
        const unsigned short* xfin1 = xss[NLAYER & 1][1];
        const int c = lane & 31, tp = lane >> 5;
        const int col = h * 32 + c;
        #pragma unroll
        for (int s = 0; s < 2; ++s) {
            const unsigned short* xf = s ? xfin1 : xfin0;
            float acc = 0.f;
            for (int t0 = 0; t0 < 40; t0 += 2) {
                int t = t0 + tp;
                if (t < NF)
                    acc += b2f(xf[t * 72 + col]) * wlinf[t * EMB + col];
            }
            #pragma unroll
            for (int off = 1; off < 64; off <<= 1)
                acc += __shfl_xor(acc, off, 64);
            if (lane == 0) red[s][wid] = acc;
        }
        __syncthreads();
        if (tid == 0) {
            att_out[samp0]     = fmaxf(red[0][0] + red[0][1], 0.f);
            att_out[samp0 + 1] = fmaxf(red[1][0] + red[1][1], 0.f);
        }
    }
}

// ------- DNN (ROUND-10 VERBATIM, frozen optimum): 32-sample tile, packed B-loads ------
// 512 blocks x 256 thr. LDS: ea 9216 + h1s 33280 = 42496 B.
__global__ void __launch_bounds__(256) dnn_kernel(
    const int* __restrict__ X,
    const float* __restrict__ embf,
    const unsigned short* __restrict__ w1p,
    const float* __restrict__ b1v,
    const unsigned short* __restrict__ w2p,
    const float* __restrict__ b2v,
    const float* __restrict__ w3v,
    const float* __restrict__ b3v,
    const float* __restrict__ att_in,
    float* __restrict__ out)
{
    __shared__ unsigned short ea[2][32 * 72];     // double-buffered [sample 32][64+8pad]
    __shared__ unsigned short h1s[32 * 520];      // h1 [32][512+8pad]; h2 [32][264] aliases
    unsigned short* h2s = h1s;

    const int tid  = threadIdx.x;
    const int wid  = tid >> 6, lane = tid & 63, quad = lane >> 4, l16 = lane & 15;
    const int S0   = blockIdx.x * 32;

    floatx4 C1[2][8];
    #pragma unroll
    for (int mt = 0; mt < 2; ++mt)
        #pragma unroll
        for (int nt = 0; nt < 8; ++nt)
            C1[mt][nt] = (floatx4){0.f, 0.f, 0.f, 0.f};

    const int gs = tid >> 3;        // 0..31 sample for staging
    const int gg = tid & 7;         // 8 floats each

    // prologue: stage field 0 into ea[0]
    {
        int row = X[(S0 + gs) * NF + 0];
        const float4* src = (const float4*)&embf[row * EMB + gg * 8];
        float4 v0 = src[0], v1 = src[1];
        uint4 u;
        u.x = cvt_pk(v0.x, v0.y); u.y = cvt_pk(v0.z, v0.w);
        u.z = cvt_pk(v1.x, v1.y); u.w = cvt_pk(v1.z, v1.w);
        *(uint4*)&ea[0][gs * 72 + gg * 8] = u;
    }
    __syncthreads();

    // ---- phase 1: h1 = emb(32 x 2496) @ W1, K streamed per field, dbuf, 1 sync/iter ---
    for (int f = 0; f < NF; ++f) {
        if (f < NF - 1) {   // stage next field into the other buffer (disjoint from reads)
            int row = X[(S0 + gs) * NF + f + 1] + (f + 1) * VOCAB;
            const float4* src = (const float4*)&embf[row * EMB + gg * 8];
            float4 v0 = src[0], v1 = src[1];
            uint4 u;
            u.x = cvt_pk(v0.x, v0.y); u.y = cvt_pk(v0.z, v0.w);
            u.z = cvt_pk(v1.x, v1.y); u.w = cvt_pk(v1.z, v1.w);
            *(uint4*)&ea[(f + 1) & 1][gs * 72 + gg * 8] = u;
        }
        const unsigned short* eac = ea[f & 1];
        short8 a[2][2];
        #pragma unroll
        for (int mt = 0; mt < 2; ++mt) {
            a[mt][0] = ld8s(&eac[(mt * 16 + l16) * 72 + quad * 8]);
            a[mt][1] = ld8s(&eac[(mt * 16 + l16) * 72 + 32 + quad * 8]);
        }
        #pragma unroll
        for (int nt = 0; nt < 8; ++nt) {
            const unsigned short* bp = w1p + (((wid * 8 + nt) * 78 + f * 2) * 64 + lane) * 8;
            short8 b0 = ld8s(bp);
            short8 b1 = ld8s(bp + 512);
            #pragma unroll
            for (int mt = 0; mt < 2; ++mt) {
                C1[mt][nt] = __builtin_amdgcn_mfma_f32_16x16x32_bf16(a[mt][0], b0, C1[mt][nt], 0, 0, 0);
                C1[mt][nt] = __builtin_amdgcn_mfma_f32_16x16x32_bf16(a[mt][1], b1, C1[mt][nt], 0, 0, 0);
            }
        }
        __syncthreads();   // waves may not drift >1 iter: protects both ea buffers
    }

    // bias + relu, write ALL of h1 to LDS (each wave owns 128 cols)
    #pragma unroll
    for (int nt = 0; nt < 8; ++nt) {
        float bb = b1v[wid * 128 + nt * 16 + l16];
        #pragma unroll
        for (int mt = 0; mt < 2; ++mt) {
            #pragma unroll
            for (int r = 0; r < 4; ++r) {
                float v = fmaxf(C1[mt][nt][r] + bb, 0.f);
                h1s[(mt * 16 + quad * 4 + r) * 520 + wid * 128 + nt * 16 + l16] = f2b(v);
            }
        }
    }
    __syncthreads();

    // ---- phase 2: h2 = h1(32 x 512) @ W2, single pass, wave owns 64 N-cols ------------
    floatx4 C2[2][4];
    #pragma unroll
    for (int mt = 0; mt < 2; ++mt)
        #pragma unroll
        for (int nt = 0; nt < 4; ++nt)
            C2[mt][nt] = (floatx4){0.f, 0.f, 0.f, 0.f};

    #pragma unroll 4
    for (int kk = 0; kk < 16; ++kk) {
        short8 a0 = ld8s(&h1s[(l16) * 520 + kk * 32 + quad * 8]);
        short8 a1 = ld8s(&h1s[(16 + l16) * 520 + kk * 32 + quad * 8]);
        #pragma unroll
        for (int nt = 0; nt < 4; ++nt) {
            short8 b = ld8s(w2p + (((wid * 4 + nt) * 16 + kk) * 64 + lane) * 8);
            C2[0][nt] = __builtin_amdgcn_mfma_f32_16x16x32_bf16(a0, b, C2[0][nt], 0, 0, 0);
            C2[1][nt] = __builtin_amdgcn_mfma_f32_16x16x32_bf16(a1, b, C2[1][nt], 0, 0, 0);
        }
    }
    __syncthreads();    // h1 reads complete -> safe to alias h2s onto h1s

    #pragma unroll
    for (int nt = 0; nt < 4; ++nt) {
        float bb = b2v[wid * 64 + nt * 16 + l16];
        #pragma unroll
        for (int mt = 0; mt < 2; ++mt)
            #pragma unroll
            for (int r = 0; r < 4; ++r)
                h2s[(mt * 16 + quad * 4 + r) * 264 + wid * 64 + nt * 16 + l16] =
                    f2b(fmaxf(C2[mt][nt][r] + bb, 0.f));
    }
    __syncthreads();

    // ---- phase 3: dnn = relu(h2 . W3 + b3); out = sigmoid(att + dnn), f32 -------------
    {
        int s = tid >> 3, part = tid & 7;     // 8 lanes per sample, 32 elems each
        float acc = 0.f;
        #pragma unroll 8
        for (int j = 0; j < 32; ++j) {
            int jj = part * 32 + j;
            acc += b2f(h2s[s * 264 + jj]) * w3v[jj];
        }
        acc += __shfl_xor(acc, 1, 64);
        acc += __shfl_xor(acc, 2, 64);
        acc += __shfl_xor(acc, 4, 64);
        if (part == 0) {
            float dnn = fmaxf(acc + b3v[0], 0.f);
            float v = dnn + att_in[S0 + s];
            out[S0 + s] = 1.f / (1.f + __expf(-v));
        }
    }
}

extern "C" void kernel_launch(void* const* d_in, const int* in_sizes, int n_in,
                              void* d_out, int out_size, void* d_ws, size_t ws_size,
                              hipStream_t stream)
{
    (void)in_sizes; (void)n_in; (void)out_size; (void)ws_size;

    const int*   X    = (const int*)d_in[0];
    const float* emb  = (const float*)d_in[1];
    const float* WQ   = (const float*)d_in[2];
    const float* WK   = (const float*)d_in[3];
    const float* WV   = (const float*)d_in[4];
    const float* WR   = (const float*)d_in[5];
    const float* W1   = (const float*)d_in[6];
    const float* b1   = (const float*)d_in[7];
    const float* W2   = (const float*)d_in[8];
    const float* b2   = (const float*)d_in[9];
    const float* W3   = (const float*)d_in[10];
    const float* b3   = (const float*)d_in[11];
    const float* Wlin = (const float*)d_in[12];

    char* ws = (char*)d_ws;
    float*          att_logit = (float*)ws;                          // 16384 f32 = 64KB
    unsigned short* wqt = (unsigned short*)(ws + 65536);             // 3*4096 shorts each
    unsigned short* wkt = wqt + 3 * 4096;
    unsigned short* wvt = wkt + 3 * 4096;
    unsigned short* wrt = wvt + 3 * 4096;
    unsigned short* w1p = wrt + 3 * 4096;                            // 2496*512 shorts
    unsigned short* w2p = w1p + 2496 * 512;                          // 256*512 shorts

    prep_all<<<880, 256, 0, stream>>>(WQ, WK, WV, WR, W1, W2,
                                      wqt, wkt, wvt, wrt, w1p, w2p);
    attn_kernel<<<8192, 128, 0, stream>>>(X, emb, wqt, wkt, wvt, wrt, Wlin, att_logit);
    dnn_kernel<<<512, 256, 0, stream>>>(X, emb, w1p, b1, w2p, b2, W3, b3, att_logit,
                                        (float*)d_out);
}